// Round 12
// baseline (273.345 us; speedup 1.0000x reference)
//
#include <hip/hip_runtime.h>
#include <hip/hip_bf16.h>
#include <math.h>

#define D_MODEL 512
#define N_HEADS 8
#define D_HEAD 64
#define D_FF 2048
#define SEQ 2048
#define BATCH 4
#define NTOK (BATCH * SEQ)
#define QSCALE 0.04419417382415922f          // 1/sqrt(512)
#define QSCALE_L2E (-QSCALE * 1.44269504089f) // fold -log2(e)*scale into Q

typedef unsigned short ushort_t;
typedef __attribute__((ext_vector_type(8))) short short8;
typedef __attribute__((ext_vector_type(4))) short short4v;
typedef __attribute__((ext_vector_type(4))) float float4v;

static __device__ __forceinline__ ushort_t f2bf(float f) {
    union { float f; unsigned int i; } c; c.f = f;
    unsigned int i = c.i;
    unsigned int r = (i + 0x7FFFu + ((i >> 16) & 1u)) >> 16;   // RNE
    return (ushort_t)r;
}

static __device__ __forceinline__ unsigned int pack2bf(float a, float b) {
    union { __hip_bfloat162 h; unsigned int u; } c;
    c.h = __float22bfloat162_rn(make_float2(a, b));
    return c.u;
}

// sigmoid with scale pre-folded: input st = -s*scale*log2e  ->  1/(1+2^st)
static __device__ __forceinline__ float sig2(float x) {
    return __builtin_amdgcn_rcpf(1.0f + __builtin_amdgcn_exp2f(x));
}

// T1: XCD-aware block swizzle (m157/m192: +10% when panel-reuse is HBM/L3-bound).
// HW round-robins hardware block id across 8 XCDs; remap so blocks resident on one XCD
// get CONTIGUOUS logical tile ids (which share operand panels -> per-XCD L2 reuse).
// Requires n % 8 == 0 (all our grids: 768/1024/256/256).
static __device__ __forceinline__ int xcdswz(int id, int n) {
    int c = n >> 3;
    return (id & 7) * c + (id >> 3);
}

// ------------- weights -> bf16 transposed [N][K], LDS-tiled (coalesced both sides) -------
__global__ __launch_bounds__(256) void k_prep_weights(const float* __restrict__ Wq,
                                                      const float* __restrict__ Wk,
                                                      const float* __restrict__ Wv,
                                                      const float* __restrict__ W1,
                                                      const float* __restrict__ W2,
                                                      ushort_t* __restrict__ Wqkvt,
                                                      ushort_t* __restrict__ W1t,
                                                      ushort_t* __restrict__ W2t) {
    __shared__ ushort_t tile[64][66];
    int bid = blockIdx.x;
    const float* src; ushort_t* dst; int K, N, tk, tn;
    if (bid < 192) {
        int m = bid >> 6, r = bid & 63;
        src = (m == 0) ? Wq : ((m == 1) ? Wk : Wv);
        dst = Wqkvt + (size_t)m * 512 * 512; K = 512; N = 512; tk = r >> 3; tn = r & 7;
    } else if (bid < 448) {
        int r = bid - 192; src = W1; dst = W1t; K = 512; N = 2048; tk = r >> 5; tn = r & 31;
    } else {
        int r = bid - 448; src = W2; dst = W2t; K = 2048; N = 512; tk = r >> 3; tn = r & 7;
    }
    int k0 = tk * 64, n0 = tn * 64;
    int rr = threadIdx.x >> 6, c = threadIdx.x & 63;
#pragma unroll
    for (int i = 0; i < 16; i++) {
        int row = i * 4 + rr;
        tile[row][c] = f2bf(src[(size_t)(k0 + row) * N + n0 + c]);
    }
    __syncthreads();
#pragma unroll
    for (int i = 0; i < 16; i++) {
        int row = i * 4 + rr;   // n-local
        dst[(size_t)(n0 + row) * K + k0 + c] = tile[c][row];
    }
}

// ---------------- layernorm: one wave per 512-wide row, out bf16 ----------------
__global__ __launch_bounds__(256) void k_layernorm(const float* __restrict__ X,
                                                   const float* __restrict__ g,
                                                   const float* __restrict__ be,
                                                   ushort_t* __restrict__ Out) {
    int row  = blockIdx.x * 4 + (threadIdx.x >> 6);
    int lane = threadIdx.x & 63;
    const float* x = X + (size_t)row * D_MODEL + lane * 8;
    float4 v0 = ((const float4*)x)[0];
    float4 v1 = ((const float4*)x)[1];
    float vals[8] = {v0.x, v0.y, v0.z, v0.w, v1.x, v1.y, v1.z, v1.w};
    float s = 0.f, sq = 0.f;
#pragma unroll
    for (int j = 0; j < 8; j++) { s += vals[j]; sq += vals[j] * vals[j]; }
#pragma unroll
    for (int off = 32; off; off >>= 1) { s += __shfl_xor(s, off); sq += __shfl_xor(sq, off); }
    float mu  = s * (1.0f / D_MODEL);
    float var = sq * (1.0f / D_MODEL) - mu * mu;
    float inv = rsqrtf(var + 1e-5f);
    const float* gp  = g  + lane * 8;
    const float* bp  = be + lane * 8;
    float4 g0 = ((const float4*)gp)[0], g1v = ((const float4*)gp)[1];
    float4 b0 = ((const float4*)bp)[0], b1v = ((const float4*)bp)[1];
    float gs[8] = {g0.x, g0.y, g0.z, g0.w, g1v.x, g1v.y, g1v.z, g1v.w};
    float bs[8] = {b0.x, b0.y, b0.z, b0.w, b1v.x, b1v.y, b1v.z, b1v.w};
    ushort_t o[8];
#pragma unroll
    for (int j = 0; j < 8; j++) o[j] = f2bf((vals[j] - mu) * inv * gs[j] + bs[j]);
    ushort_t* op = Out + (size_t)row * D_MODEL + lane * 8;
    *(uint4*)op = *(uint4*)o;
}

// ======== m97-style GEMM core: 128xBN tile, BK=32, global_load_lds double-buffer =========
static __device__ __forceinline__ void stage_tile(const ushort_t* __restrict__ G, int K,
                                                  ushort_t* L, int nchunks, int koff,
                                                  int w, int l) {
#pragma unroll
    for (int n = w; n < nchunks; n += 4) {
        const ushort_t* g = G + (size_t)(n * 16 + (l >> 2)) * K + koff + (l & 3) * 8;
        __builtin_amdgcn_global_load_lds((const __attribute__((address_space(1))) void*)g,
                                         (__attribute__((address_space(3))) void*)(L + n * 512),
                                         16, 0, 0);
    }
}

template <int JW>
static __device__ __forceinline__ void gemm_core2(const ushort_t* __restrict__ A,
                                                  const ushort_t* __restrict__ Bt,
                                                  int K, int m0, int n0,
                                                  ushort_t* As, ushort_t* Bs,
                                                  float4v acc[4][JW]) {
    const int BBUF = JW * 1024;
    int t = threadIdx.x, w = t >> 6, l = t & 63, q = l >> 4, lm = l & 15;
    int mb = (w & 1) * 64, nb = (w >> 1) * (JW * 16);
    const ushort_t* Ab = A + (size_t)m0 * K;
    const ushort_t* Bb = Bt + (size_t)n0 * K;
    int T = K >> 5;

    stage_tile(Ab, K, As, 8, 0, w, l);
    stage_tile(Bb, K, Bs, 2 * JW, 0, w, l);
    __syncthreads();

    for (int kt = 0; kt < T; kt++) {
        int cur = kt & 1;
        if (kt + 1 < T) {
            stage_tile(Ab, K, As + (1 - cur) * 4096, 8, (kt + 1) * 32, w, l);
            stage_tile(Bb, K, Bs + (1 - cur) * BBUF, 2 * JW, (kt + 1) * 32, w, l);
        }
        const ushort_t* asb = As + cur * 4096;
        const ushort_t* bsb = Bs + cur * BBUF;
        short8 a[4], b[JW];
#pragma unroll
        for (int i = 0; i < 4; i++) a[i] = *(const short8*)&asb[(mb + 16 * i + lm) * 32 + q * 8];
#pragma unroll
        for (int j = 0; j < JW; j++) b[j] = *(const short8*)&bsb[(nb + 16 * j + lm) * 32 + q * 8];
#pragma unroll
        for (int i = 0; i < 4; i++)
#pragma unroll
            for (int j = 0; j < JW; j++)
                acc[i][j] = __builtin_amdgcn_mfma_f32_16x16x32_bf16(a[i], b[j], acc[i][j], 0, 0, 0);
        __syncthreads();
    }
}

// ---------------- fused QKV projection (N=1536): q,k head-layout; v transposed ------------
__global__ __launch_bounds__(256) void k_gemm_qkv(const ushort_t* __restrict__ A,
                                                  const ushort_t* __restrict__ Bt,
                                                  const float* __restrict__ bq,
                                                  const float* __restrict__ bk,
                                                  const float* __restrict__ bv,
                                                  ushort_t* __restrict__ qb,
                                                  ushort_t* __restrict__ kb,
                                                  ushort_t* __restrict__ vt) {
    __shared__ __align__(16) ushort_t As[8192];
    __shared__ __align__(16) ushort_t Bs[8192];
    int lid = blockIdx.x + 64 * blockIdx.y;            // grid (64, 12) = 768
    lid = xcdswz(lid, 768);
    int m0 = (lid & 63) * 128, n0 = (lid >> 6) * 128;  // consecutive lids share n0 (B-panel)
    float4v acc[4][4];
#pragma unroll
    for (int i = 0; i < 4; i++)
#pragma unroll
        for (int j = 0; j < 4; j++) acc[i][j] = (float4v){0.f, 0.f, 0.f, 0.f};
    gemm_core2<4>(A, Bt, D_MODEL, m0, n0, As, Bs, acc);

    int t = threadIdx.x, w = t >> 6, l = t & 63, q = l >> 4, lm = l & 15;
    int mb = (w & 1) * 64, nb = (w >> 1) * 64;
    int mat = n0 >> 9, c0 = n0 & 511;
    const float* bias = (mat == 0) ? bq : ((mat == 1) ? bk : bv);
#pragma unroll
    for (int j = 0; j < 4; j++) {
        int cl = c0 + nb + 16 * j + lm;
        int hh = cl >> 6, dh = cl & 63;
        float bvv = bias[cl];
#pragma unroll
        for (int i = 0; i < 4; i++) {
            int mr0 = m0 + mb + 16 * i + q * 4;
            int bb = mr0 >> 11, ss0 = mr0 & (SEQ - 1);
            if (mat == 2) {
                union { ushort_t s[4]; uint2 v; } pk;
#pragma unroll
                for (int r = 0; r < 4; r++) pk.s[r] = f2bf(acc[i][j][r] + bvv);
                *(uint2*)&vt[((size_t)(bb * N_HEADS + hh) * D_HEAD + dh) * SEQ + ss0] = pk.v;
            } else {
                ushort_t* dst = (mat == 0) ? qb : kb;
                float sc = (mat == 0) ? QSCALE_L2E : 1.0f;
#pragma unroll
                for (int r = 0; r < 4; r++)
                    dst[((size_t)(bb * N_HEADS + hh) * SEQ + ss0 + r) * D_HEAD + dh] =
                        f2bf((acc[i][j][r] + bvv) * sc);
            }
        }
    }
}

// ---------------- FFN1: relu(yn @ W1 + b1) -> bf16 row-major ------------------------------
__global__ __launch_bounds__(256) void k_gemm_ffn1(const ushort_t* __restrict__ A,
                                                   const ushort_t* __restrict__ Bt,
                                                   const float* __restrict__ b1,
                                                   ushort_t* __restrict__ hb) {
    __shared__ __align__(16) ushort_t As[8192];
    __shared__ __align__(16) ushort_t Bs[8192];
    int lid = blockIdx.x + 64 * blockIdx.y;            // grid (64, 16) = 1024
    lid = xcdswz(lid, 1024);
    int m0 = (lid & 63) * 128, n0 = (lid >> 6) * 128;
    float4v acc[4][4];
#pragma unroll
    for (int i = 0; i < 4; i++)
#pragma unroll
        for (int j = 0; j < 4; j++) acc[i][j] = (float4v){0.f, 0.f, 0.f, 0.f};
    gemm_core2<4>(A, Bt, D_MODEL, m0, n0, As, Bs, acc);

    int t = threadIdx.x, w = t >> 6, l = t & 63, q = l >> 4, lm = l & 15;
    int mb = (w & 1) * 64, nb = (w >> 1) * 64;
#pragma unroll
    for (int j = 0; j < 4; j++) {
        int cl = n0 + nb + 16 * j + lm;
        float bvv = b1[cl];
#pragma unroll
        for (int i = 0; i < 4; i++) {
            int mr0 = m0 + mb + 16 * i + q * 4;
#pragma unroll
            for (int r = 0; r < 4; r++)
                hb[(size_t)(mr0 + r) * D_FF + cl] = f2bf(fmaxf(acc[i][j][r] + bvv, 0.f));
        }
    }
}

// ---------------- FFN2: hb @ W2 + b2 + residual -> f32 out (NOW 128x128 tile) -------------
// Tile ladder (m92/m103): 64-wide half-tiles cost ~2.6x vs 128^2; the old 128x64 (JW=2)
// was the weakest GEMM here despite K=2048. Same core as FFN1 (JW=4), f32+residual out.
__global__ __launch_bounds__(256) void k_gemm_ffn2(const ushort_t* __restrict__ A,
                                                   const ushort_t* __restrict__ Bt,
                                                   const float* __restrict__ b2,
                                                   const float* __restrict__ res,
                                                   float* __restrict__ out) {
    __shared__ __align__(16) ushort_t As[8192];
    __shared__ __align__(16) ushort_t Bs[8192];
    int lid = blockIdx.x + 64 * blockIdx.y;            // grid (64, 4) = 256
    lid = xcdswz(lid, 256);
    int m0 = (lid & 63) * 128, n0 = (lid >> 6) * 128;
    float4v acc[4][4];
#pragma unroll
    for (int i = 0; i < 4; i++)
#pragma unroll
        for (int j = 0; j < 4; j++) acc[i][j] = (float4v){0.f, 0.f, 0.f, 0.f};
    gemm_core2<4>(A, Bt, D_FF, m0, n0, As, Bs, acc);

    int t = threadIdx.x, w = t >> 6, l = t & 63, q = l >> 4, lm = l & 15;
    int mb = (w & 1) * 64, nb = (w >> 1) * 64;
#pragma unroll
    for (int j = 0; j < 4; j++) {
        int cl = n0 + nb + 16 * j + lm;
        float bvv = b2[cl];
#pragma unroll
        for (int i = 0; i < 4; i++) {
            int mr0 = m0 + mb + 16 * i + q * 4;
#pragma unroll
            for (int r = 0; r < 4; r++) {
                size_t idx = (size_t)(mr0 + r) * D_MODEL + cl;
                out[idx] = acc[i][j][r] + bvv + res[idx];
            }
        }
    }
}

// ---- attention helpers (byte-addressed, XOR-swizzled LDS; nt=4 wide) ---------------------
static __device__ __forceinline__ void qkt_step4(const char* __restrict__ ksb, int rowByte,
                                                 int c0, int c1,
                                                 const short8 qf[4][2], float4v st[4]) {
    short8 kf0 = *(const short8*)(ksb + rowByte + c0);
    short8 kf1 = *(const short8*)(ksb + rowByte + c1);
#pragma unroll
    for (int nt = 0; nt < 4; nt++) {
        float4v z = (float4v){0.f, 0.f, 0.f, 0.f};
        z = __builtin_amdgcn_mfma_f32_16x16x32_bf16(kf0, qf[nt][0], z, 0, 0, 0);
        z = __builtin_amdgcn_mfma_f32_16x16x32_bf16(kf1, qf[nt][1], z, 0, 0, 0);
        st[nt] = z;
    }
}

static __device__ __forceinline__ void sig_pv4(const char* __restrict__ vrow, int vcol,
                                               const float4v st[4], float4v o[4][4]) {
    short4v pf[4];
#pragma unroll
    for (int nt = 0; nt < 4; nt++) {
        union { unsigned int u[2]; short4v v; } pk;
        pk.u[0] = pack2bf(sig2(st[nt][0]), sig2(st[nt][1]));
        pk.u[1] = pack2bf(sig2(st[nt][2]), sig2(st[nt][3]));
        pf[nt] = pk.v;
    }
#pragma unroll
    for (int dj = 0; dj < 4; dj++) {
        short4v vf = *(const short4v*)(vrow + dj * 4096 + vcol);
#pragma unroll
        for (int nt = 0; nt < 4; nt++)
            o[nt][dj] = __builtin_amdgcn_mfma_f32_16x16x16bf16_1k(vf, pf[nt], o[nt][dj], 0, 0, 0);
    }
}

// ---------------- fused sigmoid attention v14: v13 + XCD swizzle --------------------------
// v13 structure (proven == v12 == v7 at 62.7us; attention dataflow is at a local fixed
// point across 6 schedule experiments). NEW: T1 XCD swizzle so all 8 s-blocks of a bh
// (sharing 512KB K/V) + 4 bh land on ONE XCD's 4MB L2 -> K/V re-reads become L2 hits
// (FETCH_SIZE 77.9MB has ~36MB of L2-miss re-fetch).
__global__ __launch_bounds__(512, 2) void k_attention(const ushort_t* __restrict__ Q,
                                                      const ushort_t* __restrict__ Kb,
                                                      const ushort_t* __restrict__ Vt,
                                                      const float* __restrict__ X,
                                                      float* __restrict__ Y) {
    __shared__ __align__(16) char smem[69632];
    char* Ks = smem;                                   // [2][128 rows][128B] swizzled
    char* Vs = smem + 32768;                           // [2][64 rows][256B] swizzled (V^T)
    float* Osum = (float*)smem;                        // after loop: 256 x 68 f32 (69.6 KB)

    const int KBUF = 16384;                            // bytes per K buffer
    const int VBUF = 16384;                            // bytes per V buffer
    const int NIT  = SEQ / 128;                        // 16

    int lid = blockIdx.x + 8 * blockIdx.y;             // grid (8, 32) = 256
    lid = xcdswz(lid, 256);
    int bh = lid >> 3;
    int s0 = (lid & 7) * 256;
    int b = bh >> 3, h = bh & 7;
    size_t base = (size_t)bh * SEQ * D_HEAD;
    int t = threadIdx.x, w = t >> 6, l = t & 63, q = l >> 4, lm = l & 15;
    int g = w >> 1, th = w & 1;

    // staging (write) offsets, loop-invariant, swizzled
    int rK = t >> 3;                                   // K shot row (0..63)
    int kOff0 = rK * 128 + (((t & 7) * 16) ^ ((rK & 7) << 4));
    int kOff1 = kOff0 + 8192;                          // +64 rows, same (row&7)
    int rV = t >> 4;                                   // V shot row (0..31)
    int vOff0 = rV * 256 + (((t & 15) * 16) ^ ((rV & 7) << 4));
    int vOff1 = vOff0 + 8192;                          // +32 rows, same (row&7)

    // read offsets, swizzled
    int swz = (lm & 7) << 4;
    int kRow0 = (64 * th + lm) * 128;                  // + mt*2048
    int kc0 = (q * 16) ^ swz;
    int kc1 = kc0 ^ 64;
    int vRowB = lm * 256;                              // + dj*4096 inside sig_pv4
    int vColBase = ((128 * th + 8 * q)) ^ swz;         // ^ (mt<<5) per mt

    // Q fragments in registers: rows s0 + 64g + 16nt + lm  (nt = 0..3)
    short8 qf[4][2];
#pragma unroll
    for (int nt = 0; nt < 4; nt++)
#pragma unroll
        for (int kc = 0; kc < 2; kc++) {
            const ushort_t* qg = Q + base + (size_t)(s0 + 64 * g + 16 * nt + lm) * D_HEAD + kc * 32 + q * 8;
            uint4 u = *(const uint4*)qg;
            qf[nt][kc] = *(const short8*)&u;
        }

    // O^T partials: o[nt][dj], lane holds O[s=s0+64g+16nt+lm][d=16dj+4q+r] (t-half partial)
    float4v o[4][4];
#pragma unroll
    for (int nt = 0; nt < 4; nt++)
#pragma unroll
        for (int dj = 0; dj < 4; dj++) o[nt][dj] = (float4v){0.f, 0.f, 0.f, 0.f};

    const ushort_t* kg0 = Kb + base + (size_t)rK * D_HEAD + (t & 7) * 8;   // global K src
    const ushort_t* vg0 = Vt + base + (size_t)rV * SEQ + (t & 15) * 8;     // global V^T src

    // prologue: tile 0 -> LDS, tile 1 -> regs
    uint4 kr0, kr1, vr0, vr1;
    kr0 = *(const uint4*)(kg0);
    kr1 = *(const uint4*)(kg0 + 64 * D_HEAD);
    vr0 = *(const uint4*)(vg0);
    vr1 = *(const uint4*)(vg0 + 32 * SEQ);
    *(uint4*)(Ks + kOff0) = kr0;
    *(uint4*)(Ks + kOff1) = kr1;
    *(uint4*)(Vs + vOff0) = vr0;
    *(uint4*)(Vs + vOff1) = vr1;
    kr0 = *(const uint4*)(kg0 + 128 * D_HEAD);
    kr1 = *(const uint4*)(kg0 + 192 * D_HEAD);
    vr0 = *(const uint4*)(vg0 + 128);
    vr1 = *(const uint4*)(vg0 + 32 * SEQ + 128);
    __syncthreads();

    for (int tt = 0; tt < NIT; tt++) {
        int cur = tt & 1;
        const char* ksb = Ks + cur * KBUF;
        const char* vsb = Vs + cur * VBUF;

        // --- issue-early: commit reg-staged tile tt+1 to other buffer; prefetch tt+2 ---
        if (tt + 1 < NIT) {
            int nxt = 1 - cur;
            *(uint4*)(Ks + nxt * KBUF + kOff0) = kr0;
            *(uint4*)(Ks + nxt * KBUF + kOff1) = kr1;
            *(uint4*)(Vs + nxt * VBUF + vOff0) = vr0;
            *(uint4*)(Vs + nxt * VBUF + vOff1) = vr1;
            if (tt + 2 < NIT) {
                size_t ko = (size_t)(tt + 2) * 128 * D_HEAD;
                size_t vo = (size_t)(tt + 2) * 128;
                kr0 = *(const uint4*)(kg0 + ko);
                kr1 = *(const uint4*)(kg0 + ko + 64 * D_HEAD);
                vr0 = *(const uint4*)(vg0 + vo);
                vr1 = *(const uint4*)(vg0 + vo + 32 * SEQ);
            }
        }

        // --- mt-rotation pipeline: QK^T(mt) overlaps sigmoid+PV(mt-1) ---
        const char* vrow = vsb + vRowB;
        float4v st[2][4];                              // [mt&1][nt], static rotation
        qkt_step4(ksb, kRow0, kc0, kc1, qf, st[0]);
#pragma unroll
        for (int mt = 1; mt < 4; mt++) {
            qkt_step4(ksb, kRow0 + 2048 * mt, kc0, kc1, qf, st[mt & 1]);
            sig_pv4(vrow, vColBase ^ ((mt - 1) << 5), st[(mt - 1) & 1], o);
        }
        sig_pv4(vrow, vColBase ^ (3 << 5), st[1], o);

        __syncthreads();
    }

    // --- pair-wave O reduction into Osum (float4; stride 68 keeps 16B alignment) ---
    if (th == 0) {
#pragma unroll
        for (int nt = 0; nt < 4; nt++)
#pragma unroll
            for (int dj = 0; dj < 4; dj++) {
                float4v v = o[nt][dj];
                *(float4*)&Osum[(64 * g + 16 * nt + lm) * 68 + 16 * dj + 4 * q] =
                    make_float4(v[0], v[1], v[2], v[3]);
            }
    }
    __syncthreads();
    if (th == 1) {
#pragma unroll
        for (int nt = 0; nt < 4; nt++)
#pragma unroll
            for (int dj = 0; dj < 4; dj++) {
                float* p = &Osum[(64 * g + 16 * nt + lm) * 68 + 16 * dj + 4 * q];
                float4 old = *(float4*)p;
                float4v v = o[nt][dj];
                *(float4*)p = make_float4(old.x + v[0], old.y + v[1], old.z + v[2], old.w + v[3]);
            }
    }
    __syncthreads();

    // --- epilogue: Y = X + O (256 rows x 64 cols; thread t: row t>>1, 32 cols) ---
    {
        int row = t >> 1, c0 = (t & 1) * 32;
        size_t gro = ((size_t)(b * SEQ + s0 + row)) * D_MODEL + h * D_HEAD + c0;
        const float* xp = X + gro;
        float* yp = Y + gro;
        const float* os = &Osum[row * 68 + c0];
#pragma unroll
        for (int i = 0; i < 8; i++) {
            float4 xv = *(const float4*)(xp + i * 4);
            float4 ov = *(const float4*)(os + i * 4);
            float4 rr;
            rr.x = xv.x + ov.x; rr.y = xv.y + ov.y;
            rr.z = xv.z + ov.z; rr.w = xv.w + ov.w;
            *(float4*)(yp + i * 4) = rr;
        }
    }
}

extern "C" void kernel_launch(void* const* d_in, const int* in_sizes, int n_in,
                              void* d_out, int out_size, void* d_ws, size_t ws_size,
                              hipStream_t stream) {
    const float* x   = (const float*)d_in[0];
    const float* Wq  = (const float*)d_in[1];
    const float* bq  = (const float*)d_in[2];
    const float* Wk  = (const float*)d_in[3];
    const float* bk  = (const float*)d_in[4];
    const float* Wv  = (const float*)d_in[5];
    const float* bv  = (const float*)d_in[6];
    const float* W1  = (const float*)d_in[7];
    const float* b1  = (const float*)d_in[8];
    const float* W2  = (const float*)d_in[9];
    const float* b2  = (const float*)d_in[10];
    const float* g1  = (const float*)d_in[11];
    const float* be1 = (const float*)d_in[12];
    const float* g2  = (const float*)d_in[13];
    const float* be2 = (const float*)d_in[14];
    float* out = (float*)d_out;

    char* p = (char*)d_ws;
    ushort_t* xn    = (ushort_t*)p; p += (size_t)NTOK * D_MODEL * 2;
    ushort_t* yn    = (ushort_t*)p; p += (size_t)NTOK * D_MODEL * 2;
    float*    y     = (float*)p;    p += (size_t)NTOK * D_MODEL * 4;
    ushort_t* qb    = (ushort_t*)p; p += (size_t)NTOK * D_MODEL * 2;
    ushort_t* kb    = (ushort_t*)p; p += (size_t)NTOK * D_MODEL * 2;
    ushort_t* vt    = (ushort_t*)p; p += (size_t)NTOK * D_MODEL * 2;
    ushort_t* hb    = (ushort_t*)p; p += (size_t)NTOK * D_FF * 2;
    ushort_t* Wqkvt = (ushort_t*)p; p += (size_t)3 * D_MODEL * D_MODEL * 2;
    ushort_t* W1t   = (ushort_t*)p; p += (size_t)D_MODEL * D_FF * 2;
    ushort_t* W2t   = (ushort_t*)p; p += (size_t)D_FF * D_MODEL * 2;

    k_prep_weights<<<704, 256, 0, stream>>>(Wq, Wk, Wv, W1, W2, Wqkvt, W1t, W2t);

    k_layernorm<<<NTOK / 4, 256, 0, stream>>>(x, g1, be1, xn);

    dim3 gq(NTOK / 128, (3 * D_MODEL) / 128);
    k_gemm_qkv<<<gq, 256, 0, stream>>>(xn, Wqkvt, bq, bk, bv, qb, kb, vt);

    dim3 ga(SEQ / 256, BATCH * N_HEADS);
    k_attention<<<ga, 512, 0, stream>>>(qb, kb, vt, x, y);

    k_layernorm<<<NTOK / 4, 256, 0, stream>>>(y, g2, be2, yn);

    dim3 g1d(NTOK / 128, D_FF / 128);
    k_gemm_ffn1<<<g1d, 256, 0, stream>>>(yn, W1t, b1, hb);
    dim3 g2d(NTOK / 128, D_MODEL / 128);
    k_gemm_ffn2<<<g2d, 256, 0, stream>>>(hb, W2t, b2, y, out);
}

// Round 13
// 269.555 us; speedup vs baseline: 1.0141x; 1.0141x over previous
//
#include <hip/hip_runtime.h>
#include <hip/hip_bf16.h>
#include <math.h>

#define D_MODEL 512
#define N_HEADS 8
#define D_HEAD 64
#define D_FF 2048
#define SEQ 2048
#define BATCH 4
#define NTOK (BATCH * SEQ)
#define QSCALE 0.04419417382415922f          // 1/sqrt(512)
#define QSCALE_L2E (-QSCALE * 1.44269504089f) // fold -log2(e)*scale into Q

typedef unsigned short ushort_t;
typedef __attribute__((ext_vector_type(8))) short short8;
typedef __attribute__((ext_vector_type(4))) short short4v;
typedef __attribute__((ext_vector_type(4))) float float4v;

static __device__ __forceinline__ ushort_t f2bf(float f) {
    union { float f; unsigned int i; } c; c.f = f;
    unsigned int i = c.i;
    unsigned int r = (i + 0x7FFFu + ((i >> 16) & 1u)) >> 16;   // RNE
    return (ushort_t)r;
}

static __device__ __forceinline__ unsigned int pack2bf(float a, float b) {
    union { __hip_bfloat162 h; unsigned int u; } c;
    c.h = __float22bfloat162_rn(make_float2(a, b));
    return c.u;
}

// sigmoid with scale pre-folded: input st = -s*scale*log2e  ->  1/(1+2^st)
static __device__ __forceinline__ float sig2(float x) {
    return __builtin_amdgcn_rcpf(1.0f + __builtin_amdgcn_exp2f(x));
}

// T1: XCD-aware block swizzle. Confirmed on attention (v14): FETCH 77.9->20.6MB.
// Requires n % 8 == 0 (grids: 768/1024/256/512).
static __device__ __forceinline__ int xcdswz(int id, int n) {
    int c = n >> 3;
    return (id & 7) * c + (id >> 3);
}

// ------------- weights -> bf16 transposed [N][K], LDS-tiled (coalesced both sides) -------
__global__ __launch_bounds__(256) void k_prep_weights(const float* __restrict__ Wq,
                                                      const float* __restrict__ Wk,
                                                      const float* __restrict__ Wv,
                                                      const float* __restrict__ W1,
                                                      const float* __restrict__ W2,
                                                      ushort_t* __restrict__ Wqkvt,
                                                      ushort_t* __restrict__ W1t,
                                                      ushort_t* __restrict__ W2t) {
    __shared__ ushort_t tile[64][66];
    int bid = blockIdx.x;
    const float* src; ushort_t* dst; int K, N, tk, tn;
    if (bid < 192) {
        int m = bid >> 6, r = bid & 63;
        src = (m == 0) ? Wq : ((m == 1) ? Wk : Wv);
        dst = Wqkvt + (size_t)m * 512 * 512; K = 512; N = 512; tk = r >> 3; tn = r & 7;
    } else if (bid < 448) {
        int r = bid - 192; src = W1; dst = W1t; K = 512; N = 2048; tk = r >> 5; tn = r & 31;
    } else {
        int r = bid - 448; src = W2; dst = W2t; K = 2048; N = 512; tk = r >> 3; tn = r & 7;
    }
    int k0 = tk * 64, n0 = tn * 64;
    int rr = threadIdx.x >> 6, c = threadIdx.x & 63;
#pragma unroll
    for (int i = 0; i < 16; i++) {
        int row = i * 4 + rr;
        tile[row][c] = f2bf(src[(size_t)(k0 + row) * N + n0 + c]);
    }
    __syncthreads();
#pragma unroll
    for (int i = 0; i < 16; i++) {
        int row = i * 4 + rr;   // n-local
        dst[(size_t)(n0 + row) * K + k0 + c] = tile[c][row];
    }
}

// ---------------- layernorm: one wave per 512-wide row, out bf16 ----------------
__global__ __launch_bounds__(256) void k_layernorm(const float* __restrict__ X,
                                                   const float* __restrict__ g,
                                                   const float* __restrict__ be,
                                                   ushort_t* __restrict__ Out) {
    int row  = blockIdx.x * 4 + (threadIdx.x >> 6);
    int lane = threadIdx.x & 63;
    const float* x = X + (size_t)row * D_MODEL + lane * 8;
    float4 v0 = ((const float4*)x)[0];
    float4 v1 = ((const float4*)x)[1];
    float vals[8] = {v0.x, v0.y, v0.z, v0.w, v1.x, v1.y, v1.z, v1.w};
    float s = 0.f, sq = 0.f;
#pragma unroll
    for (int j = 0; j < 8; j++) { s += vals[j]; sq += vals[j] * vals[j]; }
#pragma unroll
    for (int off = 32; off; off >>= 1) { s += __shfl_xor(s, off); sq += __shfl_xor(sq, off); }
    float mu  = s * (1.0f / D_MODEL);
    float var = sq * (1.0f / D_MODEL) - mu * mu;
    float inv = rsqrtf(var + 1e-5f);
    const float* gp  = g  + lane * 8;
    const float* bp  = be + lane * 8;
    float4 g0 = ((const float4*)gp)[0], g1v = ((const float4*)gp)[1];
    float4 b0 = ((const float4*)bp)[0], b1v = ((const float4*)bp)[1];
    float gs[8] = {g0.x, g0.y, g0.z, g0.w, g1v.x, g1v.y, g1v.z, g1v.w};
    float bs[8] = {b0.x, b0.y, b0.z, b0.w, b1v.x, b1v.y, b1v.z, b1v.w};
    ushort_t o[8];
#pragma unroll
    for (int j = 0; j < 8; j++) o[j] = f2bf((vals[j] - mu) * inv * gs[j] + bs[j]);
    ushort_t* op = Out + (size_t)row * D_MODEL + lane * 8;
    *(uint4*)op = *(uint4*)o;
}

// ======== m97-style GEMM core: 128xBN tile, BK=32, global_load_lds double-buffer =========
static __device__ __forceinline__ void stage_tile(const ushort_t* __restrict__ G, int K,
                                                  ushort_t* L, int nchunks, int koff,
                                                  int w, int l) {
#pragma unroll
    for (int n = w; n < nchunks; n += 4) {
        const ushort_t* g = G + (size_t)(n * 16 + (l >> 2)) * K + koff + (l & 3) * 8;
        __builtin_amdgcn_global_load_lds((const __attribute__((address_space(1))) void*)g,
                                         (__attribute__((address_space(3))) void*)(L + n * 512),
                                         16, 0, 0);
    }
}

template <int JW>
static __device__ __forceinline__ void gemm_core2(const ushort_t* __restrict__ A,
                                                  const ushort_t* __restrict__ Bt,
                                                  int K, int m0, int n0,
                                                  ushort_t* As, ushort_t* Bs,
                                                  float4v acc[4][JW]) {
    const int BBUF = JW * 1024;
    int t = threadIdx.x, w = t >> 6, l = t & 63, q = l >> 4, lm = l & 15;
    int mb = (w & 1) * 64, nb = (w >> 1) * (JW * 16);
    const ushort_t* Ab = A + (size_t)m0 * K;
    const ushort_t* Bb = Bt + (size_t)n0 * K;
    int T = K >> 5;

    stage_tile(Ab, K, As, 8, 0, w, l);
    stage_tile(Bb, K, Bs, 2 * JW, 0, w, l);
    __syncthreads();

    for (int kt = 0; kt < T; kt++) {
        int cur = kt & 1;
        if (kt + 1 < T) {
            stage_tile(Ab, K, As + (1 - cur) * 4096, 8, (kt + 1) * 32, w, l);
            stage_tile(Bb, K, Bs + (1 - cur) * BBUF, 2 * JW, (kt + 1) * 32, w, l);
        }
        const ushort_t* asb = As + cur * 4096;
        const ushort_t* bsb = Bs + cur * BBUF;
        short8 a[4], b[JW];
#pragma unroll
        for (int i = 0; i < 4; i++) a[i] = *(const short8*)&asb[(mb + 16 * i + lm) * 32 + q * 8];
#pragma unroll
        for (int j = 0; j < JW; j++) b[j] = *(const short8*)&bsb[(nb + 16 * j + lm) * 32 + q * 8];
#pragma unroll
        for (int i = 0; i < 4; i++)
#pragma unroll
            for (int j = 0; j < JW; j++)
                acc[i][j] = __builtin_amdgcn_mfma_f32_16x16x32_bf16(a[i], b[j], acc[i][j], 0, 0, 0);
        __syncthreads();
    }
}

// ---------------- fused QKV projection (N=1536): q,k head-layout; v transposed ------------
__global__ __launch_bounds__(256) void k_gemm_qkv(const ushort_t* __restrict__ A,
                                                  const ushort_t* __restrict__ Bt,
                                                  const float* __restrict__ bq,
                                                  const float* __restrict__ bk,
                                                  const float* __restrict__ bv,
                                                  ushort_t* __restrict__ qb,
                                                  ushort_t* __restrict__ kb,
                                                  ushort_t* __restrict__ vt) {
    __shared__ __align__(16) ushort_t As[8192];
    __shared__ __align__(16) ushort_t Bs[8192];
    int lid = blockIdx.x + 64 * blockIdx.y;            // grid (64, 12) = 768
    lid = xcdswz(lid, 768);
    int m0 = (lid & 63) * 128, n0 = (lid >> 6) * 128;  // consecutive lids share n0 (B-panel)
    float4v acc[4][4];
#pragma unroll
    for (int i = 0; i < 4; i++)
#pragma unroll
        for (int j = 0; j < 4; j++) acc[i][j] = (float4v){0.f, 0.f, 0.f, 0.f};
    gemm_core2<4>(A, Bt, D_MODEL, m0, n0, As, Bs, acc);

    int t = threadIdx.x, w = t >> 6, l = t & 63, q = l >> 4, lm = l & 15;
    int mb = (w & 1) * 64, nb = (w >> 1) * 64;
    int mat = n0 >> 9, c0 = n0 & 511;
    const float* bias = (mat == 0) ? bq : ((mat == 1) ? bk : bv);
#pragma unroll
    for (int j = 0; j < 4; j++) {
        int cl = c0 + nb + 16 * j + lm;
        int hh = cl >> 6, dh = cl & 63;
        float bvv = bias[cl];
#pragma unroll
        for (int i = 0; i < 4; i++) {
            int mr0 = m0 + mb + 16 * i + q * 4;
            int bb = mr0 >> 11, ss0 = mr0 & (SEQ - 1);
            if (mat == 2) {
                union { ushort_t s[4]; uint2 v; } pk;
#pragma unroll
                for (int r = 0; r < 4; r++) pk.s[r] = f2bf(acc[i][j][r] + bvv);
                *(uint2*)&vt[((size_t)(bb * N_HEADS + hh) * D_HEAD + dh) * SEQ + ss0] = pk.v;
            } else {
                ushort_t* dst = (mat == 0) ? qb : kb;
                float sc = (mat == 0) ? QSCALE_L2E : 1.0f;
#pragma unroll
                for (int r = 0; r < 4; r++)
                    dst[((size_t)(bb * N_HEADS + hh) * SEQ + ss0 + r) * D_HEAD + dh] =
                        f2bf((acc[i][j][r] + bvv) * sc);
            }
        }
    }
}

// ---------------- FFN1: relu(yn @ W1 + b1) -> bf16 row-major ------------------------------
__global__ __launch_bounds__(256) void k_gemm_ffn1(const ushort_t* __restrict__ A,
                                                   const ushort_t* __restrict__ Bt,
                                                   const float* __restrict__ b1,
                                                   ushort_t* __restrict__ hb) {
    __shared__ __align__(16) ushort_t As[8192];
    __shared__ __align__(16) ushort_t Bs[8192];
    int lid = blockIdx.x + 64 * blockIdx.y;            // grid (64, 16) = 1024
    lid = xcdswz(lid, 1024);
    int m0 = (lid & 63) * 128, n0 = (lid >> 6) * 128;
    float4v acc[4][4];
#pragma unroll
    for (int i = 0; i < 4; i++)
#pragma unroll
        for (int j = 0; j < 4; j++) acc[i][j] = (float4v){0.f, 0.f, 0.f, 0.f};
    gemm_core2<4>(A, Bt, D_MODEL, m0, n0, As, Bs, acc);

    int t = threadIdx.x, w = t >> 6, l = t & 63, q = l >> 4, lm = l & 15;
    int mb = (w & 1) * 64, nb = (w >> 1) * 64;
#pragma unroll
    for (int j = 0; j < 4; j++) {
        int cl = n0 + nb + 16 * j + lm;
        float bvv = b1[cl];
#pragma unroll
        for (int i = 0; i < 4; i++) {
            int mr0 = m0 + mb + 16 * i + q * 4;
#pragma unroll
            for (int r = 0; r < 4; r++)
                hb[(size_t)(mr0 + r) * D_FF + cl] = f2bf(fmaxf(acc[i][j][r] + bvv, 0.f));
        }
    }
}

// ---------------- FFN2: hb @ W2 + b2 + residual -> f32 out (128x64, REVERTED) -------------
// v14's 128x128 halved the grid to 256 = 1 block/CU = 1 wave/SIMD -> latency-starved
// (occupancy 9.6%, MfmaUtil 10%, 61.8us). N=512 means 128-wide tiles CANNOT fill the
// machine; 128x64 gives 512 blocks = 2/CU. Swizzle kept (B-panel L2 reuse).
__global__ __launch_bounds__(256) void k_gemm_ffn2(const ushort_t* __restrict__ A,
                                                   const ushort_t* __restrict__ Bt,
                                                   const float* __restrict__ b2,
                                                   const float* __restrict__ res,
                                                   float* __restrict__ out) {
    __shared__ __align__(16) ushort_t As[8192];
    __shared__ __align__(16) ushort_t Bs[4096];
    int lid = blockIdx.x + 64 * blockIdx.y;            // grid (64, 8) = 512
    lid = xcdswz(lid, 512);
    int m0 = (lid & 63) * 128, n0 = (lid >> 6) * 64;   // consecutive lids share n0 (B-panel)
    float4v acc[4][2];
#pragma unroll
    for (int i = 0; i < 4; i++)
#pragma unroll
        for (int j = 0; j < 2; j++) acc[i][j] = (float4v){0.f, 0.f, 0.f, 0.f};
    gemm_core2<2>(A, Bt, D_FF, m0, n0, As, Bs, acc);

    int t = threadIdx.x, w = t >> 6, l = t & 63, q = l >> 4, lm = l & 15;
    int mb = (w & 1) * 64, nb = (w >> 1) * 32;
#pragma unroll
    for (int j = 0; j < 2; j++) {
        int cl = n0 + nb + 16 * j + lm;
        float bvv = b2[cl];
#pragma unroll
        for (int i = 0; i < 4; i++) {
            int mr0 = m0 + mb + 16 * i + q * 4;
#pragma unroll
            for (int r = 0; r < 4; r++) {
                size_t idx = (size_t)(mr0 + r) * D_MODEL + cl;
                out[idx] = acc[i][j][r] + bvv + res[idx];
            }
        }
    }
}

// ---- attention helpers (byte-addressed, XOR-swizzled LDS; nt=4 wide) ---------------------
static __device__ __forceinline__ void qkt_step4(const char* __restrict__ ksb, int rowByte,
                                                 int c0, int c1,
                                                 const short8 qf[4][2], float4v st[4]) {
    short8 kf0 = *(const short8*)(ksb + rowByte + c0);
    short8 kf1 = *(const short8*)(ksb + rowByte + c1);
#pragma unroll
    for (int nt = 0; nt < 4; nt++) {
        float4v z = (float4v){0.f, 0.f, 0.f, 0.f};
        z = __builtin_amdgcn_mfma_f32_16x16x32_bf16(kf0, qf[nt][0], z, 0, 0, 0);
        z = __builtin_amdgcn_mfma_f32_16x16x32_bf16(kf1, qf[nt][1], z, 0, 0, 0);
        st[nt] = z;
    }
}

static __device__ __forceinline__ void sig_pv4(const char* __restrict__ vrow, int vcol,
                                               const float4v st[4], float4v o[4][4]) {
    short4v pf[4];
#pragma unroll
    for (int nt = 0; nt < 4; nt++) {
        union { unsigned int u[2]; short4v v; } pk;
        pk.u[0] = pack2bf(sig2(st[nt][0]), sig2(st[nt][1]));
        pk.u[1] = pack2bf(sig2(st[nt][2]), sig2(st[nt][3]));
        pf[nt] = pk.v;
    }
#pragma unroll
    for (int dj = 0; dj < 4; dj++) {
        short4v vf = *(const short4v*)(vrow + dj * 4096 + vcol);
#pragma unroll
        for (int nt = 0; nt < 4; nt++)
            o[nt][dj] = __builtin_amdgcn_mfma_f32_16x16x16bf16_1k(vf, pf[nt], o[nt][dj], 0, 0, 0);
    }
}

// ---------------- fused sigmoid attention v14: v13 + XCD swizzle (confirmed) --------------
// Swizzle verified in v14 run: FETCH 77.9 -> 20.6MB (K/V served from local XCD L2).
__global__ __launch_bounds__(512, 2) void k_attention(const ushort_t* __restrict__ Q,
                                                      const ushort_t* __restrict__ Kb,
                                                      const ushort_t* __restrict__ Vt,
                                                      const float* __restrict__ X,
                                                      float* __restrict__ Y) {
    __shared__ __align__(16) char smem[69632];
    char* Ks = smem;                                   // [2][128 rows][128B] swizzled
    char* Vs = smem + 32768;                           // [2][64 rows][256B] swizzled (V^T)
    float* Osum = (float*)smem;                        // after loop: 256 x 68 f32 (69.6 KB)

    const int KBUF = 16384;                            // bytes per K buffer
    const int VBUF = 16384;                            // bytes per V buffer
    const int NIT  = SEQ / 128;                        // 16

    int lid = blockIdx.x + 8 * blockIdx.y;             // grid (8, 32) = 256
    lid = xcdswz(lid, 256);
    int bh = lid >> 3;
    int s0 = (lid & 7) * 256;
    int b = bh >> 3, h = bh & 7;
    size_t base = (size_t)bh * SEQ * D_HEAD;
    int t = threadIdx.x, w = t >> 6, l = t & 63, q = l >> 4, lm = l & 15;
    int g = w >> 1, th = w & 1;

    // staging (write) offsets, loop-invariant, swizzled
    int rK = t >> 3;                                   // K shot row (0..63)
    int kOff0 = rK * 128 + (((t & 7) * 16) ^ ((rK & 7) << 4));
    int kOff1 = kOff0 + 8192;                          // +64 rows, same (row&7)
    int rV = t >> 4;                                   // V shot row (0..31)
    int vOff0 = rV * 256 + (((t & 15) * 16) ^ ((rV & 7) << 4));
    int vOff1 = vOff0 + 8192;                          // +32 rows, same (row&7)

    // read offsets, swizzled
    int swz = (lm & 7) << 4;
    int kRow0 = (64 * th + lm) * 128;                  // + mt*2048
    int kc0 = (q * 16) ^ swz;
    int kc1 = kc0 ^ 64;
    int vRowB = lm * 256;                              // + dj*4096 inside sig_pv4
    int vColBase = ((128 * th + 8 * q)) ^ swz;         // ^ (mt<<5) per mt

    // Q fragments in registers: rows s0 + 64g + 16nt + lm  (nt = 0..3)
    short8 qf[4][2];
#pragma unroll
    for (int nt = 0; nt < 4; nt++)
#pragma unroll
        for (int kc = 0; kc < 2; kc++) {
            const ushort_t* qg = Q + base + (size_t)(s0 + 64 * g + 16 * nt + lm) * D_HEAD + kc * 32 + q * 8;
            uint4 u = *(const uint4*)qg;
            qf[nt][kc] = *(const short8*)&u;
        }

    // O^T partials: o[nt][dj], lane holds O[s=s0+64g+16nt+lm][d=16dj+4q+r] (t-half partial)
    float4v o[4][4];
#pragma unroll
    for (int nt = 0; nt < 4; nt++)
#pragma unroll
        for (int dj = 0; dj < 4; dj++) o[nt][dj] = (float4v){0.f, 0.f, 0.f, 0.f};

    const ushort_t* kg0 = Kb + base + (size_t)rK * D_HEAD + (t & 7) * 8;   // global K src
    const ushort_t* vg0 = Vt + base + (size_t)rV * SEQ + (t & 15) * 8;     // global V^T src

    // prologue: tile 0 -> LDS, tile 1 -> regs
    uint4 kr0, kr1, vr0, vr1;
    kr0 = *(const uint4*)(kg0);
    kr1 = *(const uint4*)(kg0 + 64 * D_HEAD);
    vr0 = *(const uint4*)(vg0);
    vr1 = *(const uint4*)(vg0 + 32 * SEQ);
    *(uint4*)(Ks + kOff0) = kr0;
    *(uint4*)(Ks + kOff1) = kr1;
    *(uint4*)(Vs + vOff0) = vr0;
    *(uint4*)(Vs + vOff1) = vr1;
    kr0 = *(const uint4*)(kg0 + 128 * D_HEAD);
    kr1 = *(const uint4*)(kg0 + 192 * D_HEAD);
    vr0 = *(const uint4*)(vg0 + 128);
    vr1 = *(const uint4*)(vg0 + 32 * SEQ + 128);
    __syncthreads();

    for (int tt = 0; tt < NIT; tt++) {
        int cur = tt & 1;
        const char* ksb = Ks + cur * KBUF;
        const char* vsb = Vs + cur * VBUF;

        // --- issue-early: commit reg-staged tile tt+1 to other buffer; prefetch tt+2 ---
        if (tt + 1 < NIT) {
            int nxt = 1 - cur;
            *(uint4*)(Ks + nxt * KBUF + kOff0) = kr0;
            *(uint4*)(Ks + nxt * KBUF + kOff1) = kr1;
            *(uint4*)(Vs + nxt * VBUF + vOff0) = vr0;
            *(uint4*)(Vs + nxt * VBUF + vOff1) = vr1;
            if (tt + 2 < NIT) {
                size_t ko = (size_t)(tt + 2) * 128 * D_HEAD;
                size_t vo = (size_t)(tt + 2) * 128;
                kr0 = *(const uint4*)(kg0 + ko);
                kr1 = *(const uint4*)(kg0 + ko + 64 * D_HEAD);
                vr0 = *(const uint4*)(vg0 + vo);
                vr1 = *(const uint4*)(vg0 + vo + 32 * SEQ);
            }
        }

        // --- mt-rotation pipeline: QK^T(mt) overlaps sigmoid+PV(mt-1) ---
        const char* vrow = vsb + vRowB;
        float4v st[2][4];                              // [mt&1][nt], static rotation
        qkt_step4(ksb, kRow0, kc0, kc1, qf, st[0]);
#pragma unroll
        for (int mt = 1; mt < 4; mt++) {
            qkt_step4(ksb, kRow0 + 2048 * mt, kc0, kc1, qf, st[mt & 1]);
            sig_pv4(vrow, vColBase ^ ((mt - 1) << 5), st[(mt - 1) & 1], o);
        }
        sig_pv4(vrow, vColBase ^ (3 << 5), st[1], o);

        __syncthreads();
    }

    // --- pair-wave O reduction into Osum (float4; stride 68 keeps 16B alignment) ---
    if (th == 0) {
#pragma unroll
        for (int nt = 0; nt < 4; nt++)
#pragma unroll
            for (int dj = 0; dj < 4; dj++) {
                float4v v = o[nt][dj];
                *(float4*)&Osum[(64 * g + 16 * nt + lm) * 68 + 16 * dj + 4 * q] =
                    make_float4(v[0], v[1], v[2], v[3]);
            }
    }
    __syncthreads();
    if (th == 1) {
#pragma unroll
        for (int nt = 0; nt < 4; nt++)
#pragma unroll
            for (int dj = 0; dj < 4; dj++) {
                float* p = &Osum[(64 * g + 16 * nt + lm) * 68 + 16 * dj + 4 * q];
                float4 old = *(float4*)p;
                float4v v = o[nt][dj];
                *(float4*)p = make_float4(old.x + v[0], old.y + v[1], old.z + v[2], old.w + v[3]);
            }
    }
    __syncthreads();

    // --- epilogue: Y = X + O (256 rows x 64 cols; thread t: row t>>1, 32 cols) ---
    {
        int row = t >> 1, c0 = (t & 1) * 32;
        size_t gro = ((size_t)(b * SEQ + s0 + row)) * D_MODEL + h * D_HEAD + c0;
        const float* xp = X + gro;
        float* yp = Y + gro;
        const float* os = &Osum[row * 68 + c0];
#pragma unroll
        for (int i = 0; i < 8; i++) {
            float4 xv = *(const float4*)(xp + i * 4);
            float4 ov = *(const float4*)(os + i * 4);
            float4 rr;
            rr.x = xv.x + ov.x; rr.y = xv.y + ov.y;
            rr.z = xv.z + ov.z; rr.w = xv.w + ov.w;
            *(float4*)(yp + i * 4) = rr;
        }
    }
}

extern "C" void kernel_launch(void* const* d_in, const int* in_sizes, int n_in,
                              void* d_out, int out_size, void* d_ws, size_t ws_size,
                              hipStream_t stream) {
    const float* x   = (const float*)d_in[0];
    const float* Wq  = (const float*)d_in[1];
    const float* bq  = (const float*)d_in[2];
    const float* Wk  = (const float*)d_in[3];
    const float* bk  = (const float*)d_in[4];
    const float* Wv  = (const float*)d_in[5];
    const float* bv  = (const float*)d_in[6];
    const float* W1  = (const float*)d_in[7];
    const float* b1  = (const float*)d_in[8];
    const float* W2  = (const float*)d_in[9];
    const float* b2  = (const float*)d_in[10];
    const float* g1  = (const float*)d_in[11];
    const float* be1 = (const float*)d_in[12];
    const float* g2  = (const float*)d_in[13];
    const float* be2 = (const float*)d_in[14];
    float* out = (float*)d_out;

    char* p = (char*)d_ws;
    ushort_t* xn    = (ushort_t*)p; p += (size_t)NTOK * D_MODEL * 2;
    ushort_t* yn    = (ushort_t*)p; p += (size_t)NTOK * D_MODEL * 2;
    float*    y     = (float*)p;    p += (size_t)NTOK * D_MODEL * 4;
    ushort_t* qb    = (ushort_t*)p; p += (size_t)NTOK * D_MODEL * 2;
    ushort_t* kb    = (ushort_t*)p; p += (size_t)NTOK * D_MODEL * 2;
    ushort_t* vt    = (ushort_t*)p; p += (size_t)NTOK * D_MODEL * 2;
    ushort_t* hb    = (ushort_t*)p; p += (size_t)NTOK * D_FF * 2;
    ushort_t* Wqkvt = (ushort_t*)p; p += (size_t)3 * D_MODEL * D_MODEL * 2;
    ushort_t* W1t   = (ushort_t*)p; p += (size_t)D_MODEL * D_FF * 2;
    ushort_t* W2t   = (ushort_t*)p; p += (size_t)D_FF * D_MODEL * 2;

    k_prep_weights<<<704, 256, 0, stream>>>(Wq, Wk, Wv, W1, W2, Wqkvt, W1t, W2t);

    k_layernorm<<<NTOK / 4, 256, 0, stream>>>(x, g1, be1, xn);

    dim3 gq(NTOK / 128, (3 * D_MODEL) / 128);
    k_gemm_qkv<<<gq, 256, 0, stream>>>(xn, Wqkvt, bq, bk, bv, qb, kb, vt);

    dim3 ga(SEQ / 256, BATCH * N_HEADS);
    k_attention<<<ga, 512, 0, stream>>>(qb, kb, vt, x, y);

    k_layernorm<<<NTOK / 4, 256, 0, stream>>>(y, g2, be2, yn);

    dim3 g1d(NTOK / 128, D_FF / 128);
    k_gemm_ffn1<<<g1d, 256, 0, stream>>>(yn, W1t, b1, hb);
    dim3 g2d(NTOK / 128, D_MODEL / 64);
    k_gemm_ffn2<<<g2d, 256, 0, stream>>>(hb, W2t, b2, y, out);
}